// Round 21
// baseline (45.265 us; speedup 1.0000x reference)
//
#include <hip/hip_runtime.h>
#include <hip/hip_bf16.h>

constexpr int kN = 8, kC = 128, kH = 64, kW = 64, kO = 128;
constexpr int kHW = kH * kW;

typedef float f32x2 __attribute__((ext_vector_type(2)));
typedef float f32x4 __attribute__((ext_vector_type(4)));
typedef float f32x16 __attribute__((ext_vector_type(16)));
typedef short bf16x8 __attribute__((ext_vector_type(8)));
typedef unsigned short ushort8 __attribute__((ext_vector_type(8)));
typedef unsigned int u32x4 __attribute__((ext_vector_type(4)));

__device__ __forceinline__ float bf2f(unsigned short u) {
  unsigned int x = ((unsigned int)u) << 16;
  return __builtin_bit_cast(float, x);
}
__device__ __forceinline__ unsigned short f2bf(float f) {
  unsigned int b = __builtin_bit_cast(unsigned int, f);
  b += 0x7FFFu + ((b >> 16) & 1u);  // RNE
  return (unsigned short)(b >> 16);
}
// unpack a u32 holding bf16 pair (elem 2t low, 2t+1 high) -> f32x2
__device__ __forceinline__ f32x2 bf2x2(unsigned int u) {
  f32x2 r;
  r[0] = __builtin_bit_cast(float, u << 16);
  r[1] = __builtin_bit_cast(float, u & 0xFFFF0000u);
  return r;
}

#define GLOAD_LDS16(g, l)                                              \
  __builtin_amdgcn_global_load_lds(                                    \
      (const __attribute__((address_space(1))) void*)(g),              \
      (__attribute__((address_space(3))) void*)(l), 16, 0, 0)

// ============================================================================
// prep (+ folded weight reorder): VERBATIM R14-R20 (verified passing).
// ============================================================================
__global__ __launch_bounds__(256) void prep_kernel(
    const float* __restrict__ inp, const float* __restrict__ ste_w,
    const float* __restrict__ ste_b, const float* __restrict__ bn_g,
    const float* __restrict__ bn_b, const float* __restrict__ bn_m,
    const float* __restrict__ bn_v, unsigned short* __restrict__ nhwc,
    float* __restrict__ prm, const float* __restrict__ dw,
    unsigned short* __restrict__ wkb) {
  const int bid = blockIdx.x;
  if (bid >= kN * kH) {  // ---- folded reorder branch (block-uniform) ----
    int idx = (bid - kN * kH) * 256 + threadIdx.x;
    if (idx < 9 * kO * kC) {
      int k = idx / (kO * kC);
      int r = idx - k * (kO * kC);
      int o = r >> 7, c = r & 127;
      int c8 = c >> 3;
      int dstc = ((c8 ^ (o & 7)) << 3) | (c & 7);  // pre-swizzled slot
      wkb[k * (kO * kC) + (o << 7) + dstc] = f2bf(dw[(o * kC + c) * 9 + k]);
    }
    return;
  }

  __shared__ __align__(16) float tile[kC * kW];  // 32 KB, XOR-swizzled slots
  __shared__ float part[16][3][kW];              // 12 KB partial dots
  const int tid = threadIdx.x;
  const int nh = bid;
  const int n = nh >> 6, h = nh & 63;
  const float* base = inp + (size_t)n * kC * kHW + h * kW;

  // ---- phase 1: float4 load + swizzled LDS store + fused STE partials ----
  const int w4 = tid & 15;   // float4 column
  const int m = tid >> 4;    // c-group
  float p0[4] = {0.f, 0.f, 0.f, 0.f};
  float p1[4] = {0.f, 0.f, 0.f, 0.f};
  float p2[4] = {0.f, 0.f, 0.f, 0.f};
#pragma unroll
  for (int it = 0; it < 8; ++it) {
    const int c = m + it * 16;
    f32x4 v = *(const f32x4*)(base + c * kHW + w4 * 4);
    ((f32x4*)tile)[c * 16 + (w4 ^ ((c >> 3) & 7))] = v;
    const float s0 = ste_w[c], s1 = ste_w[kC + c], s2 = ste_w[2 * kC + c];
#pragma unroll
    for (int e = 0; e < 4; ++e) {
      p0[e] += s0 * v[e];
      p1[e] += s1 * v[e];
      p2[e] += s2 * v[e];
    }
  }
#pragma unroll
  for (int e = 0; e < 4; ++e) {
    part[m][0][w4 * 4 + e] = p0[e];
    part[m][1][w4 * 4 + e] = p1[e];
    part[m][2][w4 * 4 + e] = p2[e];
  }
  __syncthreads();  // tile + part ready

  // ---- phase 2a: final reduce + STE/BN/tanh params (tid < 64) ----
  if (tid < kW) {
    const int w = tid;
    float s0 = 0.f, s1 = 0.f, s2 = 0.f;
#pragma unroll
    for (int g = 0; g < 16; ++g) {
      s0 += part[g][0][w];
      s1 += part[g][1][w];
      s2 += part[g][2][w];
    }
    s0 = (s0 + ste_b[0] - bn_m[0]) * (bn_g[0] * rsqrtf(bn_v[0] + 1e-5f)) + bn_b[0];
    s1 = (s1 + ste_b[1] - bn_m[1]) * (bn_g[1] * rsqrtf(bn_v[1] + 1e-5f)) + bn_b[1];
    s2 = (s2 + ste_b[2] - bn_m[2]) * (bn_g[2] * rsqrtf(bn_v[2] + 1e-5f)) + bn_b[2];
    float th = tanhf(s0) * (3.14f / 6.0f);
    float i1 = tanhf(s1) * 0.75f + 0.75f;
    float i2 = tanhf(s2) * 0.75f + 0.75f;
    float sn = sinf(th), cs = cosf(th);
    prm[nh * 192 + w * 3 + 0] = cs * i1;  // a00
    prm[nh * 192 + w * 3 + 1] = sn;       // sin
    prm[nh * 192 + w * 3 + 2] = cs * i2;  // a11
  }

  // ---- phase 2b: NHWC bf16 write, coalesced (ch fastest across lanes) ----
#pragma unroll
  for (int it = 0; it < 4; ++it) {
    int i = tid + it * 256;  // [0,1024)
    int ch = i & 15, w = i >> 4;
    int c0 = ch * 8;
    const int xw = (((w >> 2) ^ (ch & 7)) << 2) + (w & 3);  // (c0+j)>>3 == ch
    ushort8 v;
#pragma unroll
    for (int j = 0; j < 8; ++j) v[j] = f2bf(tile[(c0 + j) * kW + xw]);
    *(ushort8*)&nhwc[((size_t)(n * kH + h) * kW + w) * kC + c0] = v;
  }
}

// ============================================================================
// MFMA main kernel: VERBATIM R20 except ONE change — s_setprio(1) around the
// per-tap MFMA cluster (T5). The CU hosts 2 independent blocks whose waves
// sit at different phases (gather/DMA-issue vs MFMA) — the role-diversity
// precondition under which setprio was +4-7% (attn, m191); m190's GEMM null
// was a lockstep structure. Zero numerics change.
// ============================================================================
__global__ __launch_bounds__(512, 4) void deform_mfma_kernel(
    const unsigned short* __restrict__ nhwc,
    const unsigned short* __restrict__ wkb,
    const float* __restrict__ prm, const float* __restrict__ db,
    float* __restrict__ out) {
  __shared__ __align__(16) unsigned short As[2][32 * 128];   // 2 x 8 KB
  __shared__ __align__(16) unsigned short Bs[2][128 * 128];  // 2 x 32 KB

  const int tid = threadIdx.x;
  const int lane = tid & 63, wave = tid >> 6;
  // ---- XCD-aware bijective swizzle (nwg = 1024 = 8 * 128) ----
  const int wid = (blockIdx.x & 7) * 128 + (blockIdx.x >> 3);
  const int nh = wid >> 1;
  const int w0 = (wid & 1) << 5;
  const int n = nh >> 6, h = nh & 63;
  const unsigned short* nhwc_n = nhwc + (size_t)n * kH * kW * kC;

  // ---- per-thread A-build assignment & params (p fixed per thread) ----
  const int p = tid >> 4, ch = tid & 15;
  const int cb = ch * 8;
  const float a00 = prm[nh * 192 + (w0 + p) * 3 + 0];
  const float sn  = prm[nh * 192 + (w0 + p) * 3 + 1];
  const float a11 = prm[nh * 192 + (w0 + p) * 3 + 2];

  // ---- wave -> (N-quadrant, K-half) decomposition ----
  const int q = wave >> 1;       // N-quadrant 0..3 (o = q*32..q*32+31)
  const int khalf = wave & 1;    // K 64-half within each tap
  const int arow = lane & 31;
  const int brow = q * 32 + (lane & 31);
  const int koff = (lane >> 5) * 16;  // byte offset of k-sub (R8-verified)
  const int aswz = (arow & 7) << 4;
  const int bswz = (brow & 7) << 4;

  f32x16 acc;
#pragma unroll
  for (int j = 0; j < 16; ++j) acc[j] = 0.f;

  // two in-flight A-gather sets (alternated by compile-time k&1)
  u32x4 aC0[4], aC1[4];
  float wgt0[4], wgt1[4];

  // ---- B staging: 4 DMA ops/wave, fully linear 32 KB copy ----
  auto issue_B = [&](int k, int buf) {
    const char* gk = (const char*)wkb + (size_t)k * 32768;
    char* lb = (char*)Bs[buf];
    const int wo = wave * 1024;
    const int lo16 = lane * 16;
#pragma unroll
    for (int it = 0; it < 4; ++it) {
      GLOAD_LDS16(gk + it * 8192 + wo + lo16, lb + it * 8192 + wo);
    }
  };

  // issue gathers for tap k into set (aC, wgt) — R6-verified math
  auto gather_A = [&](int k, u32x4* aC, float* wgt) {
    const float fdy = (float)(k / 3 - 1);
    const float fdx = (float)(k % 3 - 1);
    const float o0 = fdy;
    const float o1 = (k == 2) ? -1.0f : fdx;  // OFF row 2 duplicates row 0
    float y = (float)h + fdy + o0 * a00 + o1 * sn;
    float x = (float)(w0 + p) + fdx - o0 * sn + o1 * a11;
    float y0f = floorf(y), x0f = floorf(x);
    float wy = y - y0f, wx = x - x0f;
    int y0 = (int)y0f, x0 = (int)x0f;
    bool yv0 = (unsigned)y0 < (unsigned)kH;
    bool yv1 = (unsigned)(y0 + 1) < (unsigned)kH;
    bool xv0 = (unsigned)x0 < (unsigned)kW;
    bool xv1 = (unsigned)(x0 + 1) < (unsigned)kW;
    int y0c = min(max(y0, 0), kH - 1);
    int y1c = min(max(y0 + 1, 0), kH - 1);
    int x0c = min(max(x0, 0), kW - 1);
    int x1c = min(max(x0 + 1, 0), kW - 1);
    wgt[0] = (1.f - wy) * (1.f - wx) * (yv0 && xv0 ? 1.f : 0.f);
    wgt[1] = (1.f - wy) * wx * (yv0 && xv1 ? 1.f : 0.f);
    wgt[2] = wy * (1.f - wx) * (yv1 && xv0 ? 1.f : 0.f);
    wgt[3] = wy * wx * (yv1 && xv1 ? 1.f : 0.f);
    aC[0] = *(const u32x4*)&nhwc_n[((y0c * kW) + x0c) * kC + cb];
    aC[1] = *(const u32x4*)&nhwc_n[((y0c * kW) + x1c) * kC + cb];
    aC[2] = *(const u32x4*)&nhwc_n[((y1c * kW) + x0c) * kC + cb];
    aC[3] = *(const u32x4*)&nhwc_n[((y1c * kW) + x1c) * kC + cb];
  };

  // packed interp from set (aC, wgt) -> swizzled As[buf]
  auto write_A = [&](int buf, const u32x4* aC, const float* wgt) {
    u32x4 r;
#pragma unroll
    for (int t = 0; t < 4; ++t) {
      f32x2 v = bf2x2(aC[0][t]) * wgt[0] + bf2x2(aC[1][t]) * wgt[1] +
                bf2x2(aC[2][t]) * wgt[2] + bf2x2(aC[3][t]) * wgt[3];
      __hip_bfloat162 pk = __float22bfloat162_rn(float2{v[0], v[1]});
      unsigned int bits;
      __builtin_memcpy(&bits, &pk, 4);
      r[t] = bits;
    }
    *(u32x4*)((char*)As[buf] + p * 256 + ((ch * 16) ^ ((p & 7) << 4))) = r;
  };

  // counted-vmcnt raw barrier: own B-DMA + own LDS writes drained; the 4
  // newest VMEM ops (A-gathers) stay in flight across the barrier.
  auto barrier_v4 = [&]() {
    asm volatile("s_waitcnt vmcnt(4) lgkmcnt(0)" ::: "memory");
    __builtin_amdgcn_sched_barrier(0);
    __builtin_amdgcn_s_barrier();
  };
  auto barrier_v0 = [&]() {
    asm volatile("s_waitcnt vmcnt(0) lgkmcnt(0)" ::: "memory");
    __builtin_amdgcn_sched_barrier(0);
    __builtin_amdgcn_s_barrier();
  };

  // ---- prologue: B(0) oldest, gathers(1) newest ----
  issue_B(0, 0);
  gather_A(0, aC0, wgt0);
  write_A(0, aC0, wgt0);      // consumes gathers(0) via compiler waits
  gather_A(1, aC1, wgt1);     // 4 newest — float across the barrier
  barrier_v4();               // drains B(0) + As writes only

  // ---- pipelined tap loop: 2-deep A pipeline, counted-vmcnt barriers ----
#pragma unroll
  for (int k = 0; k < 9; ++k) {
    const int cur = k & 1;
    if (k < 8) issue_B(k + 1, cur ^ 1);  // issue B FIRST (older than gathers)
    if (k < 7) {
      if (cur == 0) gather_A(k + 2, aC0, wgt0);
      else          gather_A(k + 2, aC1, wgt1);
    }

    const char* Ab = (const char*)As[cur] + arow * 256;
    const char* Bb = (const char*)Bs[cur] + brow * 256;
    __builtin_amdgcn_s_setprio(1);
#pragma unroll
    for (int c = 0; c < 4; ++c) {
      const int kb = (khalf * 4 + c) * 32 + koff;
      bf16x8 a = *(const bf16x8*)(Ab + (kb ^ aswz));
      bf16x8 b = *(const bf16x8*)(Bb + (kb ^ bswz));
      acc = __builtin_amdgcn_mfma_f32_32x32x16_bf16(a, b, acc, 0, 0, 0);
    }
    __builtin_amdgcn_s_setprio(0);

    if (k < 8) {
      if (cur == 0) write_A(cur ^ 1, aC1, wgt1);
      else          write_A(cur ^ 1, aC0, wgt0);
    }

    if (k < 7) barrier_v4();        // gathers(k+2) float; B(k+1) drained
    else if (k == 7) barrier_v0();  // only B(8) outstanding — drain it
    else __syncthreads();           // k==8: full drain before epilogue
  }

  // ---- epilogue: cross-wave K-half reduce (conflict-free scalar LDS),
  //      then R8-verified 32x32 C/D mapping write ----
  float* red = (float*)&Bs[0][0];  // 32 KB, free after last barrier
  if (khalf == 1) {
#pragma unroll
    for (int j = 0; j < 16; ++j) red[q * 1024 + j * 64 + lane] = acc[j];
  }
  __syncthreads();
  if (khalf == 0) {
#pragma unroll
    for (int j = 0; j < 16; ++j) acc[j] += red[q * 1024 + j * 64 + lane];
    const int o = q * 32 + (lane & 31);
    const float bias = db[o];
    float* obase = out + ((size_t)(n * kO + o)) * kHW + h * kW + w0 +
                   4 * (lane >> 5);
#pragma unroll
    for (int qq = 0; qq < 4; ++qq) {
      float4 v = {acc[4 * qq + 0] + bias, acc[4 * qq + 1] + bias,
                  acc[4 * qq + 2] + bias, acc[4 * qq + 3] + bias};
      *(float4*)&obase[8 * qq] = v;
    }
  }
}

// ============================================================================
// Fallback (fp32, no workspace) — verbatim.
// ============================================================================
__global__ __launch_bounds__(256) void deform_kernel_f32(
    const float* __restrict__ inp, const float* __restrict__ ste_w,
    const float* __restrict__ ste_b, const float* __restrict__ bn_g,
    const float* __restrict__ bn_b, const float* __restrict__ bn_m,
    const float* __restrict__ bn_v, const float* __restrict__ dw,
    const float* __restrict__ db, float* __restrict__ out) {
  __shared__ __align__(16) float smp[kC * 16];
  __shared__ float prm[16][3];
  const int tid = threadIdx.x;
  const int base = blockIdx.x * 16;
  const int n = base / kHW;
  const int hw = base - n * kHW;
  const int h = hw / kW;
  const int w0 = hw - h * kW;
  const float* inp_n = inp + (size_t)n * kC * kHW;

  for (int i = tid; i < kC * 16; i += 256) {
    int c = i >> 4, p = i & 15;
    smp[i] = inp_n[c * kHW + h * kW + w0 + p];
  }
  __syncthreads();
  {
    const int p = tid >> 4, cl = tid & 15;
    float a0 = 0.f, a1 = 0.f, a2 = 0.f;
#pragma unroll
    for (int i = 0; i < 8; ++i) {
      int c = cl + (i << 4);
      float v = smp[c * 16 + p];
      a0 += v * ste_w[c];
      a1 += v * ste_w[kC + c];
      a2 += v * ste_w[2 * kC + c];
    }
#pragma unroll
    for (int off = 8; off; off >>= 1) {
      a0 += __shfl_down(a0, off, 16);
      a1 += __shfl_down(a1, off, 16);
      a2 += __shfl_down(a2, off, 16);
    }
    if (cl == 0) {
      float s0 = (a0 + ste_b[0] - bn_m[0]) * (bn_g[0] * rsqrtf(bn_v[0] + 1e-5f)) + bn_b[0];
      float s1 = (a1 + ste_b[1] - bn_m[1]) * (bn_g[1] * rsqrtf(bn_v[1] + 1e-5f)) + bn_b[1];
      float s2 = (a2 + ste_b[2] - bn_m[2]) * (bn_g[2] * rsqrtf(bn_v[2] + 1e-5f)) + bn_b[2];
      float th = tanhf(s0) * (3.14f / 6.0f);
      float i1 = tanhf(s1) * 0.75f + 0.75f;
      float i2 = tanhf(s2) * 0.75f + 0.75f;
      prm[p][0] = cosf(th) * i1;
      prm[p][1] = sinf(th);
      prm[p][2] = cosf(th) * i2;
    }
  }
  const int o = tid & 127;
  const int ph = tid >> 7;
  float acc[8] = {0.f};
  for (int k = 0; k < 9; ++k) {
    __syncthreads();
    const float fdy = (float)(k / 3 - 1);
    const float fdx = (float)(k % 3 - 1);
    const float o0 = fdy;
    const float o1 = (k == 2) ? -1.0f : fdx;
    for (int i = tid; i < kC * 16; i += 256) {
      int c = i >> 4, p = i & 15;
      float a00 = prm[p][0], sn = prm[p][1], a11 = prm[p][2];
      float y = (float)h + fdy + o0 * a00 + o1 * sn;
      float x = (float)(w0 + p) + fdx - o0 * sn + o1 * a11;
      float y0f = floorf(y), x0f = floorf(x);
      float wy = y - y0f, wx = x - x0f;
      int y0 = (int)y0f, x0 = (int)x0f;
      const float* ic = inp_n + c * kHW;
      bool yv0 = (unsigned)y0 < (unsigned)kH;
      bool yv1 = (unsigned)(y0 + 1) < (unsigned)kH;
      bool xv0 = (unsigned)x0 < (unsigned)kW;
      bool xv1 = (unsigned)(x0 + 1) < (unsigned)kW;
      int y0c = min(max(y0, 0), kH - 1);
      int y1c = min(max(y0 + 1, 0), kH - 1);
      int x0c = min(max(x0, 0), kW - 1);
      int x1c = min(max(x0 + 1, 0), kW - 1);
      float v00 = (yv0 && xv0) ? ic[y0c * kW + x0c] : 0.f;
      float v01 = (yv0 && xv1) ? ic[y0c * kW + x1c] : 0.f;
      float v10 = (yv1 && xv0) ? ic[y1c * kW + x0c] : 0.f;
      float v11 = (yv1 && xv1) ? ic[y1c * kW + x1c] : 0.f;
      smp[i] = v00 * (1.f - wy) * (1.f - wx) + v01 * (1.f - wy) * wx +
               v10 * wy * (1.f - wx) + v11 * wy * wx;
    }
    __syncthreads();
    const float* wp = dw + (size_t)o * kC * 9 + k;
#pragma unroll 4
    for (int c = 0; c < kC; ++c) {
      float wv = wp[(size_t)c * 9];
      const float4 s0 = *(const float4*)&smp[c * 16 + (ph << 3)];
      const float4 s1 = *(const float4*)&smp[c * 16 + (ph << 3) + 4];
      acc[0] += wv * s0.x; acc[1] += wv * s0.y; acc[2] += wv * s0.z; acc[3] += wv * s0.w;
      acc[4] += wv * s1.x; acc[5] += wv * s1.y; acc[6] += wv * s1.z; acc[7] += wv * s1.w;
    }
  }
  const float bias = db[o];
  float* op = out + ((size_t)(n * kO + o)) * kHW + h * kW + w0 + (ph << 3);
#pragma unroll
  for (int j = 0; j < 8; ++j) op[j] = acc[j] + bias;
}

extern "C" void kernel_launch(void* const* d_in, const int* in_sizes, int n_in,
                              void* d_out, int out_size, void* d_ws, size_t ws_size,
                              hipStream_t stream) {
  const float* inp   = (const float*)d_in[0];
  const float* ste_w = (const float*)d_in[1];
  const float* ste_b = (const float*)d_in[2];
  const float* bn_g  = (const float*)d_in[3];
  const float* bn_b  = (const float*)d_in[4];
  const float* bn_m  = (const float*)d_in[5];
  const float* bn_v  = (const float*)d_in[6];
  const float* dw    = (const float*)d_in[7];
  const float* db    = (const float*)d_in[8];
  float* out = (float*)d_out;

  const size_t nhwc_bytes = (size_t)kN * kH * kW * kC * 2;
  const size_t wkb_bytes = (size_t)9 * kO * kC * 2;
  const size_t prm_bytes = (size_t)kN * kH * kW * 3 * 4;
  const size_t need = nhwc_bytes + wkb_bytes + prm_bytes;

  if (ws_size >= need) {
    unsigned short* nhwc = (unsigned short*)d_ws;
    unsigned short* wkb = (unsigned short*)((char*)d_ws + nhwc_bytes);
    float* prm = (float*)((char*)d_ws + nhwc_bytes + wkb_bytes);
    const int reorder_blocks = (9 * kO * kC + 255) / 256;  // 576
    prep_kernel<<<kN * kH + reorder_blocks, 256, 0, stream>>>(
        inp, ste_w, ste_b, bn_g, bn_b, bn_m, bn_v, nhwc, prm, dw, wkb);
    deform_mfma_kernel<<<kN * kH * 2, 512, 0, stream>>>(nhwc, wkb, prm, db, out);
  } else {
    deform_kernel_f32<<<kN * kHW / 16, 256, 0, stream>>>(
        inp, ste_w, ste_b, bn_g, bn_b, bn_m, bn_v, dw, db, out);
  }
}

// Round 22
// 44.685 us; speedup vs baseline: 1.0130x; 1.0130x over previous
//
#include <hip/hip_runtime.h>
#include <hip/hip_bf16.h>

constexpr int kN = 8, kC = 128, kH = 64, kW = 64, kO = 128;
constexpr int kHW = kH * kW;

typedef float f32x2 __attribute__((ext_vector_type(2)));
typedef float f32x4 __attribute__((ext_vector_type(4)));
typedef float f32x16 __attribute__((ext_vector_type(16)));
typedef short bf16x8 __attribute__((ext_vector_type(8)));
typedef unsigned short ushort8 __attribute__((ext_vector_type(8)));
typedef unsigned int u32x4 __attribute__((ext_vector_type(4)));

__device__ __forceinline__ float bf2f(unsigned short u) {
  unsigned int x = ((unsigned int)u) << 16;
  return __builtin_bit_cast(float, x);
}
__device__ __forceinline__ unsigned short f2bf(float f) {
  unsigned int b = __builtin_bit_cast(unsigned int, f);
  b += 0x7FFFu + ((b >> 16) & 1u);  // RNE
  return (unsigned short)(b >> 16);
}
// unpack a u32 holding bf16 pair (elem 2t low, 2t+1 high) -> f32x2
__device__ __forceinline__ f32x2 bf2x2(unsigned int u) {
  f32x2 r;
  r[0] = __builtin_bit_cast(float, u << 16);
  r[1] = __builtin_bit_cast(float, u & 0xFFFF0000u);
  return r;
}

#define GLOAD_LDS16(g, l)                                              \
  __builtin_amdgcn_global_load_lds(                                    \
      (const __attribute__((address_space(1))) void*)(g),              \
      (__attribute__((address_space(3))) void*)(l), 16, 0, 0)

// ============================================================================
// prep (+ folded weight reorder): VERBATIM R14-R21 (verified passing).
// ============================================================================
__global__ __launch_bounds__(256) void prep_kernel(
    const float* __restrict__ inp, const float* __restrict__ ste_w,
    const float* __restrict__ ste_b, const float* __restrict__ bn_g,
    const float* __restrict__ bn_b, const float* __restrict__ bn_m,
    const float* __restrict__ bn_v, unsigned short* __restrict__ nhwc,
    float* __restrict__ prm, const float* __restrict__ dw,
    unsigned short* __restrict__ wkb) {
  const int bid = blockIdx.x;
  if (bid >= kN * kH) {  // ---- folded reorder branch (block-uniform) ----
    int idx = (bid - kN * kH) * 256 + threadIdx.x;
    if (idx < 9 * kO * kC) {
      int k = idx / (kO * kC);
      int r = idx - k * (kO * kC);
      int o = r >> 7, c = r & 127;
      int c8 = c >> 3;
      int dstc = ((c8 ^ (o & 7)) << 3) | (c & 7);  // pre-swizzled slot
      wkb[k * (kO * kC) + (o << 7) + dstc] = f2bf(dw[(o * kC + c) * 9 + k]);
    }
    return;
  }

  __shared__ __align__(16) float tile[kC * kW];  // 32 KB, XOR-swizzled slots
  __shared__ float part[16][3][kW];              // 12 KB partial dots
  const int tid = threadIdx.x;
  const int nh = bid;
  const int n = nh >> 6, h = nh & 63;
  const float* base = inp + (size_t)n * kC * kHW + h * kW;

  // ---- phase 1: float4 load + swizzled LDS store + fused STE partials ----
  const int w4 = tid & 15;   // float4 column
  const int m = tid >> 4;    // c-group
  float p0[4] = {0.f, 0.f, 0.f, 0.f};
  float p1[4] = {0.f, 0.f, 0.f, 0.f};
  float p2[4] = {0.f, 0.f, 0.f, 0.f};
#pragma unroll
  for (int it = 0; it < 8; ++it) {
    const int c = m + it * 16;
    f32x4 v = *(const f32x4*)(base + c * kHW + w4 * 4);
    ((f32x4*)tile)[c * 16 + (w4 ^ ((c >> 3) & 7))] = v;
    const float s0 = ste_w[c], s1 = ste_w[kC + c], s2 = ste_w[2 * kC + c];
#pragma unroll
    for (int e = 0; e < 4; ++e) {
      p0[e] += s0 * v[e];
      p1[e] += s1 * v[e];
      p2[e] += s2 * v[e];
    }
  }
#pragma unroll
  for (int e = 0; e < 4; ++e) {
    part[m][0][w4 * 4 + e] = p0[e];
    part[m][1][w4 * 4 + e] = p1[e];
    part[m][2][w4 * 4 + e] = p2[e];
  }
  __syncthreads();  // tile + part ready

  // ---- phase 2a: final reduce + STE/BN/tanh params (tid < 64) ----
  if (tid < kW) {
    const int w = tid;
    float s0 = 0.f, s1 = 0.f, s2 = 0.f;
#pragma unroll
    for (int g = 0; g < 16; ++g) {
      s0 += part[g][0][w];
      s1 += part[g][1][w];
      s2 += part[g][2][w];
    }
    s0 = (s0 + ste_b[0] - bn_m[0]) * (bn_g[0] * rsqrtf(bn_v[0] + 1e-5f)) + bn_b[0];
    s1 = (s1 + ste_b[1] - bn_m[1]) * (bn_g[1] * rsqrtf(bn_v[1] + 1e-5f)) + bn_b[1];
    s2 = (s2 + ste_b[2] - bn_m[2]) * (bn_g[2] * rsqrtf(bn_v[2] + 1e-5f)) + bn_b[2];
    float th = tanhf(s0) * (3.14f / 6.0f);
    float i1 = tanhf(s1) * 0.75f + 0.75f;
    float i2 = tanhf(s2) * 0.75f + 0.75f;
    float sn = sinf(th), cs = cosf(th);
    prm[nh * 192 + w * 3 + 0] = cs * i1;  // a00
    prm[nh * 192 + w * 3 + 1] = sn;       // sin
    prm[nh * 192 + w * 3 + 2] = cs * i2;  // a11
  }

  // ---- phase 2b: NHWC bf16 write, coalesced (ch fastest across lanes) ----
#pragma unroll
  for (int it = 0; it < 4; ++it) {
    int i = tid + it * 256;  // [0,1024)
    int ch = i & 15, w = i >> 4;
    int c0 = ch * 8;
    const int xw = (((w >> 2) ^ (ch & 7)) << 2) + (w & 3);  // (c0+j)>>3 == ch
    ushort8 v;
#pragma unroll
    for (int j = 0; j < 8; ++j) v[j] = f2bf(tile[(c0 + j) * kW + xw]);
    *(ushort8*)&nhwc[((size_t)(n * kH + h) * kW + w) * kC + c0] = v;
  }
}

// ============================================================================
// MFMA main kernel: VERBATIM R20 (best: 44.93 µs) — setprio reverted (R21
// measured it slightly negative; counted-vmcnt barriers keep waves
// phase-locked, so no role diversity for the scheduler to exploit).
// Structure: block = (n,h,w-half), M=32, N=128, 512 thr = 4 N-quadrants x
// 2 K-halves (32x32x16 MFMA), 80 KB LDS dbuf, 2 blocks/CU, XCD-bijective
// swizzle, B via pre-swizzled global_load_lds DMA, 2-tap-deep A-gather
// pipeline, counted-vmcnt(4) raw barriers, packed f32x2 interp.
// ============================================================================
__global__ __launch_bounds__(512, 4) void deform_mfma_kernel(
    const unsigned short* __restrict__ nhwc,
    const unsigned short* __restrict__ wkb,
    const float* __restrict__ prm, const float* __restrict__ db,
    float* __restrict__ out) {
  __shared__ __align__(16) unsigned short As[2][32 * 128];   // 2 x 8 KB
  __shared__ __align__(16) unsigned short Bs[2][128 * 128];  // 2 x 32 KB

  const int tid = threadIdx.x;
  const int lane = tid & 63, wave = tid >> 6;
  // ---- XCD-aware bijective swizzle (nwg = 1024 = 8 * 128) ----
  const int wid = (blockIdx.x & 7) * 128 + (blockIdx.x >> 3);
  const int nh = wid >> 1;
  const int w0 = (wid & 1) << 5;
  const int n = nh >> 6, h = nh & 63;
  const unsigned short* nhwc_n = nhwc + (size_t)n * kH * kW * kC;

  // ---- per-thread A-build assignment & params (p fixed per thread) ----
  const int p = tid >> 4, ch = tid & 15;
  const int cb = ch * 8;
  const float a00 = prm[nh * 192 + (w0 + p) * 3 + 0];
  const float sn  = prm[nh * 192 + (w0 + p) * 3 + 1];
  const float a11 = prm[nh * 192 + (w0 + p) * 3 + 2];

  // ---- wave -> (N-quadrant, K-half) decomposition ----
  const int q = wave >> 1;       // N-quadrant 0..3 (o = q*32..q*32+31)
  const int khalf = wave & 1;    // K 64-half within each tap
  const int arow = lane & 31;
  const int brow = q * 32 + (lane & 31);
  const int koff = (lane >> 5) * 16;  // byte offset of k-sub (R8-verified)
  const int aswz = (arow & 7) << 4;
  const int bswz = (brow & 7) << 4;

  f32x16 acc;
#pragma unroll
  for (int j = 0; j < 16; ++j) acc[j] = 0.f;

  // two in-flight A-gather sets (alternated by compile-time k&1)
  u32x4 aC0[4], aC1[4];
  float wgt0[4], wgt1[4];

  // ---- B staging: 4 DMA ops/wave, fully linear 32 KB copy ----
  auto issue_B = [&](int k, int buf) {
    const char* gk = (const char*)wkb + (size_t)k * 32768;
    char* lb = (char*)Bs[buf];
    const int wo = wave * 1024;
    const int lo16 = lane * 16;
#pragma unroll
    for (int it = 0; it < 4; ++it) {
      GLOAD_LDS16(gk + it * 8192 + wo + lo16, lb + it * 8192 + wo);
    }
  };

  // issue gathers for tap k into set (aC, wgt) — R6-verified math
  auto gather_A = [&](int k, u32x4* aC, float* wgt) {
    const float fdy = (float)(k / 3 - 1);
    const float fdx = (float)(k % 3 - 1);
    const float o0 = fdy;
    const float o1 = (k == 2) ? -1.0f : fdx;  // OFF row 2 duplicates row 0
    float y = (float)h + fdy + o0 * a00 + o1 * sn;
    float x = (float)(w0 + p) + fdx - o0 * sn + o1 * a11;
    float y0f = floorf(y), x0f = floorf(x);
    float wy = y - y0f, wx = x - x0f;
    int y0 = (int)y0f, x0 = (int)x0f;
    bool yv0 = (unsigned)y0 < (unsigned)kH;
    bool yv1 = (unsigned)(y0 + 1) < (unsigned)kH;
    bool xv0 = (unsigned)x0 < (unsigned)kW;
    bool xv1 = (unsigned)(x0 + 1) < (unsigned)kW;
    int y0c = min(max(y0, 0), kH - 1);
    int y1c = min(max(y0 + 1, 0), kH - 1);
    int x0c = min(max(x0, 0), kW - 1);
    int x1c = min(max(x0 + 1, 0), kW - 1);
    wgt[0] = (1.f - wy) * (1.f - wx) * (yv0 && xv0 ? 1.f : 0.f);
    wgt[1] = (1.f - wy) * wx * (yv0 && xv1 ? 1.f : 0.f);
    wgt[2] = wy * (1.f - wx) * (yv1 && xv0 ? 1.f : 0.f);
    wgt[3] = wy * wx * (yv1 && xv1 ? 1.f : 0.f);
    aC[0] = *(const u32x4*)&nhwc_n[((y0c * kW) + x0c) * kC + cb];
    aC[1] = *(const u32x4*)&nhwc_n[((y0c * kW) + x1c) * kC + cb];
    aC[2] = *(const u32x4*)&nhwc_n[((y1c * kW) + x0c) * kC + cb];
    aC[3] = *(const u32x4*)&nhwc_n[((y1c * kW) + x1c) * kC + cb];
  };

  // packed interp from set (aC, wgt) -> swizzled As[buf]
  auto write_A = [&](int buf, const u32x4* aC, const float* wgt) {
    u32x4 r;
#pragma unroll
    for (int t = 0; t < 4; ++t) {
      f32x2 v = bf2x2(aC[0][t]) * wgt[0] + bf2x2(aC[1][t]) * wgt[1] +
                bf2x2(aC[2][t]) * wgt[2] + bf2x2(aC[3][t]) * wgt[3];
      __hip_bfloat162 pk = __float22bfloat162_rn(float2{v[0], v[1]});
      unsigned int bits;
      __builtin_memcpy(&bits, &pk, 4);
      r[t] = bits;
    }
    *(u32x4*)((char*)As[buf] + p * 256 + ((ch * 16) ^ ((p & 7) << 4))) = r;
  };

  // counted-vmcnt raw barrier: own B-DMA + own LDS writes drained; the 4
  // newest VMEM ops (A-gathers) stay in flight across the barrier.
  auto barrier_v4 = [&]() {
    asm volatile("s_waitcnt vmcnt(4) lgkmcnt(0)" ::: "memory");
    __builtin_amdgcn_sched_barrier(0);
    __builtin_amdgcn_s_barrier();
  };
  auto barrier_v0 = [&]() {
    asm volatile("s_waitcnt vmcnt(0) lgkmcnt(0)" ::: "memory");
    __builtin_amdgcn_sched_barrier(0);
    __builtin_amdgcn_s_barrier();
  };

  // ---- prologue: B(0) oldest, gathers(1) newest ----
  issue_B(0, 0);
  gather_A(0, aC0, wgt0);
  write_A(0, aC0, wgt0);      // consumes gathers(0) via compiler waits
  gather_A(1, aC1, wgt1);     // 4 newest — float across the barrier
  barrier_v4();               // drains B(0) + As writes only

  // ---- pipelined tap loop: 2-deep A pipeline, counted-vmcnt barriers ----
#pragma unroll
  for (int k = 0; k < 9; ++k) {
    const int cur = k & 1;
    if (k < 8) issue_B(k + 1, cur ^ 1);  // issue B FIRST (older than gathers)
    if (k < 7) {
      if (cur == 0) gather_A(k + 2, aC0, wgt0);
      else          gather_A(k + 2, aC1, wgt1);
    }

    const char* Ab = (const char*)As[cur] + arow * 256;
    const char* Bb = (const char*)Bs[cur] + brow * 256;
#pragma unroll
    for (int c = 0; c < 4; ++c) {
      const int kb = (khalf * 4 + c) * 32 + koff;
      bf16x8 a = *(const bf16x8*)(Ab + (kb ^ aswz));
      bf16x8 b = *(const bf16x8*)(Bb + (kb ^ bswz));
      acc = __builtin_amdgcn_mfma_f32_32x32x16_bf16(a, b, acc, 0, 0, 0);
    }

    if (k < 8) {
      if (cur == 0) write_A(cur ^ 1, aC1, wgt1);
      else          write_A(cur ^ 1, aC0, wgt0);
    }

    if (k < 7) barrier_v4();        // gathers(k+2) float; B(k+1) drained
    else if (k == 7) barrier_v0();  // only B(8) outstanding — drain it
    else __syncthreads();           // k==8: full drain before epilogue
  }

  // ---- epilogue: cross-wave K-half reduce (conflict-free scalar LDS),
  //      then R8-verified 32x32 C/D mapping write ----
  float* red = (float*)&Bs[0][0];  // 32 KB, free after last barrier
  if (khalf == 1) {
#pragma unroll
    for (int j = 0; j < 16; ++j) red[q * 1024 + j * 64 + lane] = acc[j];
  }
  __syncthreads();
  if (khalf == 0) {
#pragma unroll
    for (int j = 0; j < 16; ++j) acc[j] += red[q * 1024 + j * 64 + lane];
    const int o = q * 32 + (lane & 31);
    const float bias = db[o];
    float* obase = out + ((size_t)(n * kO + o)) * kHW + h * kW + w0 +
                   4 * (lane >> 5);
#pragma unroll
    for (int qq = 0; qq < 4; ++qq) {
      float4 v = {acc[4 * qq + 0] + bias, acc[4 * qq + 1] + bias,
                  acc[4 * qq + 2] + bias, acc[4 * qq + 3] + bias};
      *(float4*)&obase[8 * qq] = v;
    }
  }
}

// ============================================================================
// Fallback (fp32, no workspace) — verbatim.
// ============================================================================
__global__ __launch_bounds__(256) void deform_kernel_f32(
    const float* __restrict__ inp, const float* __restrict__ ste_w,
    const float* __restrict__ ste_b, const float* __restrict__ bn_g,
    const float* __restrict__ bn_b, const float* __restrict__ bn_m,
    const float* __restrict__ bn_v, const float* __restrict__ dw,
    const float* __restrict__ db, float* __restrict__ out) {
  __shared__ __align__(16) float smp[kC * 16];
  __shared__ float prm[16][3];
  const int tid = threadIdx.x;
  const int base = blockIdx.x * 16;
  const int n = base / kHW;
  const int hw = base - n * kHW;
  const int h = hw / kW;
  const int w0 = hw - h * kW;
  const float* inp_n = inp + (size_t)n * kC * kHW;

  for (int i = tid; i < kC * 16; i += 256) {
    int c = i >> 4, p = i & 15;
    smp[i] = inp_n[c * kHW + h * kW + w0 + p];
  }
  __syncthreads();
  {
    const int p = tid >> 4, cl = tid & 15;
    float a0 = 0.f, a1 = 0.f, a2 = 0.f;
#pragma unroll
    for (int i = 0; i < 8; ++i) {
      int c = cl + (i << 4);
      float v = smp[c * 16 + p];
      a0 += v * ste_w[c];
      a1 += v * ste_w[kC + c];
      a2 += v * ste_w[2 * kC + c];
    }
#pragma unroll
    for (int off = 8; off; off >>= 1) {
      a0 += __shfl_down(a0, off, 16);
      a1 += __shfl_down(a1, off, 16);
      a2 += __shfl_down(a2, off, 16);
    }
    if (cl == 0) {
      float s0 = (a0 + ste_b[0] - bn_m[0]) * (bn_g[0] * rsqrtf(bn_v[0] + 1e-5f)) + bn_b[0];
      float s1 = (a1 + ste_b[1] - bn_m[1]) * (bn_g[1] * rsqrtf(bn_v[1] + 1e-5f)) + bn_b[1];
      float s2 = (a2 + ste_b[2] - bn_m[2]) * (bn_g[2] * rsqrtf(bn_v[2] + 1e-5f)) + bn_b[2];
      float th = tanhf(s0) * (3.14f / 6.0f);
      float i1 = tanhf(s1) * 0.75f + 0.75f;
      float i2 = tanhf(s2) * 0.75f + 0.75f;
      prm[p][0] = cosf(th) * i1;
      prm[p][1] = sinf(th);
      prm[p][2] = cosf(th) * i2;
    }
  }
  const int o = tid & 127;
  const int ph = tid >> 7;
  float acc[8] = {0.f};
  for (int k = 0; k < 9; ++k) {
    __syncthreads();
    const float fdy = (float)(k / 3 - 1);
    const float fdx = (float)(k % 3 - 1);
    const float o0 = fdy;
    const float o1 = (k == 2) ? -1.0f : fdx;
    for (int i = tid; i < kC * 16; i += 256) {
      int c = i >> 4, p = i & 15;
      float a00 = prm[p][0], sn = prm[p][1], a11 = prm[p][2];
      float y = (float)h + fdy + o0 * a00 + o1 * sn;
      float x = (float)(w0 + p) + fdx - o0 * sn + o1 * a11;
      float y0f = floorf(y), x0f = floorf(x);
      float wy = y - y0f, wx = x - x0f;
      int y0 = (int)y0f, x0 = (int)x0f;
      const float* ic = inp_n + c * kHW;
      bool yv0 = (unsigned)y0 < (unsigned)kH;
      bool yv1 = (unsigned)(y0 + 1) < (unsigned)kH;
      bool xv0 = (unsigned)x0 < (unsigned)kW;
      bool xv1 = (unsigned)(x0 + 1) < (unsigned)kW;
      int y0c = min(max(y0, 0), kH - 1);
      int y1c = min(max(y0 + 1, 0), kH - 1);
      int x0c = min(max(x0, 0), kW - 1);
      int x1c = min(max(x0 + 1, 0), kW - 1);
      float v00 = (yv0 && xv0) ? ic[y0c * kW + x0c] : 0.f;
      float v01 = (yv0 && xv1) ? ic[y0c * kW + x1c] : 0.f;
      float v10 = (yv1 && xv0) ? ic[y1c * kW + x0c] : 0.f;
      float v11 = (yv1 && xv1) ? ic[y1c * kW + x1c] : 0.f;
      smp[i] = v00 * (1.f - wy) * (1.f - wx) + v01 * (1.f - wy) * wx +
               v10 * wy * (1.f - wx) + v11 * wy * wx;
    }
    __syncthreads();
    const float* wp = dw + (size_t)o * kC * 9 + k;
#pragma unroll 4
    for (int c = 0; c < kC; ++c) {
      float wv = wp[(size_t)c * 9];
      const float4 s0 = *(const float4*)&smp[c * 16 + (ph << 3)];
      const float4 s1 = *(const float4*)&smp[c * 16 + (ph << 3) + 4];
      acc[0] += wv * s0.x; acc[1] += wv * s0.y; acc[2] += wv * s0.z; acc[3] += wv * s0.w;
      acc[4] += wv * s1.x; acc[5] += wv * s1.y; acc[6] += wv * s1.z; acc[7] += wv * s1.w;
    }
  }
  const float bias = db[o];
  float* op = out + ((size_t)(n * kO + o)) * kHW + h * kW + w0 + (ph << 3);
#pragma unroll
  for (int j = 0; j < 8; ++j) op[j] = acc[j] + bias;
}

extern "C" void kernel_launch(void* const* d_in, const int* in_sizes, int n_in,
                              void* d_out, int out_size, void* d_ws, size_t ws_size,
                              hipStream_t stream) {
  const float* inp   = (const float*)d_in[0];
  const float* ste_w = (const float*)d_in[1];
  const float* ste_b = (const float*)d_in[2];
  const float* bn_g  = (const float*)d_in[3];
  const float* bn_b  = (const float*)d_in[4];
  const float* bn_m  = (const float*)d_in[5];
  const float* bn_v  = (const float*)d_in[6];
  const float* dw    = (const float*)d_in[7];
  const float* db    = (const float*)d_in[8];
  float* out = (float*)d_out;

  const size_t nhwc_bytes = (size_t)kN * kH * kW * kC * 2;
  const size_t wkb_bytes = (size_t)9 * kO * kC * 2;
  const size_t prm_bytes = (size_t)kN * kH * kW * 3 * 4;
  const size_t need = nhwc_bytes + wkb_bytes + prm_bytes;

  if (ws_size >= need) {
    unsigned short* nhwc = (unsigned short*)d_ws;
    unsigned short* wkb = (unsigned short*)((char*)d_ws + nhwc_bytes);
    float* prm = (float*)((char*)d_ws + nhwc_bytes + wkb_bytes);
    const int reorder_blocks = (9 * kO * kC + 255) / 256;  // 576
    prep_kernel<<<kN * kH + reorder_blocks, 256, 0, stream>>>(
        inp, ste_w, ste_b, bn_g, bn_b, bn_m, bn_v, nhwc, prm, dw, wkb);
    deform_mfma_kernel<<<kN * kH * 2, 512, 0, stream>>>(nhwc, wkb, prm, db, out);
  } else {
    deform_kernel_f32<<<kN * kHW / 16, 256, 0, stream>>>(
        inp, ste_w, ste_b, bn_g, bn_b, bn_m, bn_v, dw, db, out);
  }
}